// Round 8
// baseline (1177.202 us; speedup 1.0000x reference)
//
#include <hip/hip_runtime.h>
#include <math.h>

#define NN 100000
#define EE 500000
#define ET 64
#define NPAD 500032          // 7813 * 64
#define NEB  7813
#define NNB  1563            // ceil(100000/64)

typedef __attribute__((ext_vector_type(8))) short short8;
typedef __attribute__((ext_vector_type(4))) float f32x4;
typedef __attribute__((ext_vector_type(16))) float f32x16;

// LDS chunk swizzle: 16B chunks, XOR row&7 into chunk index (T2, §6 G4)
#define C32(row, ch) (((row)<<5) + ((ch) ^ ((row)&7)))           // [*][256] bf16 buffers
#define C16(row, ch) (((row)<<4) + ((ch) ^ ((row)&7)))           // [*][128] bf16 buffers
#define E16(row, col) ((C16((row),(col)>>3)<<3) + ((col)&7))
#define Z16 (f32x16){0,0,0,0,0,0,0,0,0,0,0,0,0,0,0,0}
#define ROWOF(g,hi) (((g)&3) + 8*((g)>>2) + 4*(hi))

__device__ __forceinline__ f32x4 mfma16(short8 a, short8 b, f32x4 c){
    return __builtin_amdgcn_mfma_f32_16x16x32_bf16(a, b, c, 0, 0, 0);
}
__device__ __forceinline__ f32x16 mfma32(short8 a, short8 b, f32x16 c){
    return __builtin_amdgcn_mfma_f32_32x32x16_bf16(a, b, c, 0, 0, 0);
}
__device__ __forceinline__ short f2bf(float f){
    union { float f; unsigned u; } v; v.f = f;
    unsigned r = v.u + 0x7fffu + ((v.u >> 16) & 1u);
    return (short)(r >> 16);
}
__device__ __forceinline__ float bf2f(short s){
    union { unsigned u; float f; } v; v.u = ((unsigned)(unsigned short)s) << 16;
    return v.f;
}
// B fragment for 16x16x32 (node kernel): col=lane&15 (+16*ct), k=ks*32+(lane>>4)*8
__device__ __forceinline__ short8 bfrag(const short* __restrict__ W, int K, int ct, int ks, int lane){
    return *(const short8*)(W + (long)(ct*16 + (lane&15))*K + ks*32 + (lane>>4)*8);
}
// B fragment for 32x32x16: col=colbase+(lane&31), k=kc*16+(lane>>5)*8
__device__ __forceinline__ short8 bfrag32(const short* __restrict__ W, int K, int colbase, int kc, int lane){
    return *(const short8*)(W + (long)(colbase + (lane&31))*K + kc*16 + (lane>>5)*8);
}

// ---------------- Prep: convert ALL stage weights to bf16 in ws ----------------
__global__ __launch_bounds__(256) void prep_kernel(
    const float* __restrict__ ent_w, const float* __restrict__ q_w,
    const float* __restrict__ k_w,   const float* __restrict__ v_w,
    const float* __restrict__ meas_w,const float* __restrict__ out_w,
    const float* __restrict__ sp_w,  const float* __restrict__ amp_w,
    const float* __restrict__ ph_w,
    short* __restrict__ dst)
{
    int i = blockIdx.x*256 + threadIdx.x;   // 221184 total
    float v;
    if      (i <  65536) v = ent_w[i];
    else if (i <  81920) v = q_w[i-65536];
    else if (i <  98304) v = k_w[i-81920];
    else if (i < 114688) v = v_w[i-98304];
    else if (i < 180224) v = meas_w[i-114688];
    else if (i < 196608) v = out_w[i-180224];
    else if (i < 212992) v = sp_w[i-196608];
    else if (i < 217088) v = amp_w[i-212992];
    else                 v = ph_w[i-217088];
    dst[i] = f2bf(v);
}

// ---------------- Sort pipeline: counting sort of edges by tgt ----------------
__global__ __launch_bounds__(256) void hist_kernel(const int* __restrict__ eidx, int* __restrict__ hist){
    int i = blockIdx.x*256 + threadIdx.x;
    if (i < EE) atomicAdd(&hist[eidx[EE+i]], 1);
}
__global__ __launch_bounds__(512) void scanA_kernel(const int* __restrict__ hist,
                                                    int* __restrict__ scanv, int* __restrict__ bsum){
    __shared__ int s[512];
    const int tid = threadIdx.x;
    const int i = blockIdx.x*512 + tid;
    int v = hist[i];
    s[tid] = v;
    __syncthreads();
    #pragma unroll
    for (int d=1; d<512; d<<=1){
        int t = (tid>=d) ? s[tid-d] : 0;
        __syncthreads();
        s[tid] += t;
        __syncthreads();
    }
    scanv[i] = s[tid] - v;
    if (tid==511) bsum[blockIdx.x] = s[511];
}
__global__ __launch_bounds__(256) void scanB_kernel(const int* __restrict__ bsum, int* __restrict__ boff){
    __shared__ int s[256];
    const int tid = threadIdx.x;
    int v = (tid<196) ? bsum[tid] : 0;
    s[tid] = v;
    __syncthreads();
    #pragma unroll
    for (int d=1; d<256; d<<=1){
        int t = (tid>=d) ? s[tid-d] : 0;
        __syncthreads();
        s[tid] += t;
        __syncthreads();
    }
    if (tid<196) boff[tid] = s[tid] - v;
}
__global__ __launch_bounds__(256) void scatter_kernel(const int* __restrict__ eidx,
    const int* __restrict__ scanv, const int* __restrict__ boff, int* __restrict__ cnt,
    int* __restrict__ sTgt, int* __restrict__ sSrc)
{
    int i = blockIdx.x*256 + threadIdx.x;
    if (i >= EE) return;
    int t = eidx[EE+i], sv = eidx[i];
    int r = atomicAdd(&cnt[t], 1);
    int pos = scanv[t] + boff[t>>9] + r;
    sTgt[pos] = t; sSrc[pos] = sv;
}

// ---------------- Stage 1: node prep via MFMA, 64 nodes/block ----------------
__global__ __launch_bounds__(512) void node_kernel(
    const float* __restrict__ x,
    const short* __restrict__ wSP, const float* __restrict__ sp_b,
    const float* __restrict__ ln1_g, const float* __restrict__ ln1_b,
    const float* __restrict__ pg,
    const short* __restrict__ wA, const float* __restrict__ amp_b,
    const short* __restrict__ wP, const float* __restrict__ ph_b,
    short* __restrict__ qfb)
{
    __shared__ short xb[64*128];
    __shared__ float yb[64*132];
    __shared__ short qsb[64*128];
    __shared__ float pgs[64];

    const int tid = threadIdx.x;
    const int lane = tid & 63;
    const int w    = tid >> 6;
    const int l15  = lane & 15;
    const int lj   = (lane >> 4) << 2;
    const int n0   = blockIdx.x * 64;

    if (tid < 64){
        float s = 0.f;
        #pragma unroll
        for (int r=0;r<8;r++) s += pg[r*64 + tid];
        pgs[tid] = s;
    }
    for (int t = tid; t < 1024; t += 512){
        int e = t >> 4, c8 = t & 15;
        int n = n0 + e; if (n >= NN) n = NN-1;
        const float4* xg = (const float4*)(x + (long)n*128 + c8*8);
        float4 a = xg[0], b = xg[1];
        short8 sv;
        sv[0]=f2bf(a.x); sv[1]=f2bf(a.y); sv[2]=f2bf(a.z); sv[3]=f2bf(a.w);
        sv[4]=f2bf(b.x); sv[5]=f2bf(b.y); sv[6]=f2bf(b.z); sv[7]=f2bf(b.w);
        ((short8*)xb)[C16(e, c8)] = sv;
    }
    __syncthreads();

    const short8* xbv = (const short8*)xb;
    const int col = (w<<4) + l15;

    {
        f32x4 acc[4];
        #pragma unroll
        for (int r=0;r<4;r++) acc[r]=(f32x4){0,0,0,0};
        #pragma unroll
        for (int ks=0; ks<4; ks++){
            short8 bw = bfrag(wSP,128,w,ks,lane);
            #pragma unroll
            for (int r=0;r<4;r++){
                int row = r*16+l15;
                acc[r] = mfma16(xbv[(row<<4) + (((ks<<2)+(lane>>4)) ^ (row&7))], bw, acc[r]);
            }
        }
        float bias = sp_b[col];
        #pragma unroll
        for (int r=0;r<4;r++){
            #pragma unroll
            for (int j=0;j<4;j++)
                yb[(r*16+lj+j)*132 + col] = acc[r][j] + bias;
        }
    }
    __syncthreads();

    {
        const int row = tid >> 3, cs = tid & 7;
        float v[16];
        float s = 0.f, sq = 0.f;
        #pragma unroll
        for (int i=0;i<16;i++){
            v[i] = yb[row*132 + cs*16 + i];
            s += v[i]; sq += v[i]*v[i];
        }
        #pragma unroll
        for (int m=1;m<8;m<<=1){ s += __shfl_xor(s,m); sq += __shfl_xor(sq,m); }
        float mean = s*(1.0f/128.0f);
        float rstd = rsqrtf(sq*(1.0f/128.0f) - mean*mean + 1e-5f);
        short8 s0, s1;
        #pragma unroll
        for (int i=0;i<16;i++){
            int c = cs*16 + i;
            float q = tanhf((v[i]-mean)*rstd*ln1_g[c] + ln1_b[c]);
            if (i<8) s0[i] = f2bf(q); else s1[i-8] = f2bf(q);
        }
        ((short8*)qsb)[C16(row, cs*2  )] = s0;
        ((short8*)qsb)[C16(row, cs*2+1)] = s1;
    }
    __syncthreads();

    {
        const short8* qv = (const short8*)qsb;
        const int isPh = w >> 2;
        const int ct   = w & 3;
        f32x4 a4[4];
        #pragma unroll
        for (int r=0;r<4;r++) a4[r]=(f32x4){0,0,0,0};
        #pragma unroll
        for (int ks=0; ks<2; ks++){
            short8 bw = bfrag(isPh ? wP : wA, 64, ct, ks, lane);
            #pragma unroll
            for (int r=0;r<4;r++){
                int row = r*16+l15;
                int ch = isPh*8 + (ks<<2)+(lane>>4);
                a4[r] = mfma16(qv[(row<<4) + (ch ^ (row&7))], bw, a4[r]);
            }
        }
        const int oc = ct*16 + l15;
        float bs = isPh ? ph_b[oc] : amp_b[oc];
        #pragma unroll
        for (int r=0;r<4;r++){
            #pragma unroll
            for (int j=0;j<4;j++){
                float vv = a4[r][j] + bs;
                float ov = isPh ? tanhf(vv)*3.14159265358979323846f
                                : 1.0f/(1.0f+expf(-vv));
                yb[(r*16+lj+j)*132 + isPh*64 + oc] = ov;
            }
        }
    }
    __syncthreads();

    {
        const int row = tid >> 3, cs = tid & 7;
        const int n = n0 + row;
        short8 outc, outs;
        #pragma unroll
        for (int i=0;i<8;i++){
            int c = cs*8 + i;
            float amp  = yb[row*132 + c];
            float ph   = yb[row*132 + 64 + c];
            float real = bf2f(qsb[E16(row, c)]);
            float ang  = ph + real*pgs[c];
            outc[i] = f2bf(amp * cosf(ang));
            outs[i] = f2bf(amp * sinf(ang));
        }
        if (n < NN){
            *(short8*)(qfb + (long)n*128 + cs*8)      = outc;
            *(short8*)(qfb + (long)n*128 + 64 + cs*8) = outs;
        }
    }
}

// ---------------- Stage 2: per-edge message via 32x32x16 MFMA ----------------
// Wave w -> row-half rh=w>>2 (rows 32rh..+31), col-strip cs=w&3 (cols 32cs..+31).
// C/D layout (m74/m101): col=lane&31, row=(g&3)+8*(g>>2)+4*(lane>>5).
__global__ __launch_bounds__(512) void edge_kernel(
    const short* __restrict__ qfb,
    const int* __restrict__ sTgt, const int* __restrict__ sSrc,
    const short* __restrict__ wE, const float* __restrict__ ent_b,
    const short* __restrict__ wQ, const float* __restrict__ q_b,
    const short* __restrict__ wK, const float* __restrict__ k_b,
    const short* __restrict__ wV, const float* __restrict__ v_b,
    const short* __restrict__ wM, const float* __restrict__ meas_b,
    const short* __restrict__ wO, const float* __restrict__ out_b,
    float* __restrict__ agg)
{
    __shared__ short xin[ET*256];    // 32KB [xi|xj] C32; msgb overlays [0:16KB] after ENT
    __shared__ short ebuf[ET*256];   // 32KB [ei|ej] C32; msgF f32[64][128] overlays after MEAS
    __shared__ float part[ET][9];
    __shared__ float swv[ET][5];
    __shared__ int tg[ET], srr[ET];
    __shared__ int tgPrevS, tgNextS;

    short* msgb = xin;
    float* msgF = (float*)ebuf;

    // bijective XCD-chunked swizzle (m204)
    const int nwg = gridDim.x, orig = blockIdx.x;
    const int qd = nwg>>3, rm = nwg&7, xc = orig&7, oo = orig>>3;
    const int bid = (xc<rm ? xc*(qd+1) : rm*(qd+1)+(xc-rm)*qd) + oo;

    const int tid  = threadIdx.x;
    const int lane = tid & 63;
    const int w    = tid >> 6;
    const long e0  = (long)bid * ET;
    const int rh   = w >> 2;
    const int cs   = w & 3;
    const int l31  = lane & 31;
    const int hi   = lane >> 5;
    const int r0   = rh << 5;
    const int colg = (cs<<5) + l31;

    if (tid < ET) { tg[tid] = sTgt[e0+tid]; srr[tid] = sSrc[e0+tid]; }
    if (tid == 64) tgPrevS = (e0 > 0)      ? sTgt[e0-1]  : -2;
    if (tid == 65) tgNextS = (e0+ET < NPAD)? sTgt[e0+ET] : -2;
    __syncthreads();

    for (int t = tid; t < ET*32; t += 512) {
        int e = t >> 5, c8 = t & 31;
        int node = (c8 < 16) ? tg[e] : srr[e];
        if (node < 0) node = 0;
        short8 val = ((const short8*)(qfb + (long)node*128))[c8 & 15];
        ((short8*)xin)[C32(e, c8)] = val;
    }
    __syncthreads();                 // S1

    const short8* xinv = (const short8*)xin;

    // ---- QKV: one pass over xi/xj frags; scores reduced in-register ----
    f32x16 av;
    {
        f32x16 aq = Z16, ak = Z16;
        av = Z16;
        #pragma unroll
        for (int kc=0; kc<8; kc++){
            short8 fi = xinv[C32(r0+l31, kc*2+hi)];
            short8 fj = xinv[C32(r0+l31, 16+kc*2+hi)];
            aq = mfma32(fi, bfrag32(wQ,128,cs<<5,kc,lane), aq);
            ak = mfma32(fj, bfrag32(wK,128,cs<<5,kc,lane), ak);
            av = mfma32(fj, bfrag32(wV,128,cs<<5,kc,lane), av);
        }
        float qb_ = q_b[colg], kb_ = k_b[colg];
        float p[16];
        #pragma unroll
        for (int g=0; g<16; g++) p[g] = (aq[g]+qb_)*(ak[g]+kb_);
        #pragma unroll
        for (int m=1; m<32; m<<=1){
            #pragma unroll
            for (int g=0; g<16; g++) p[g] += __shfl_xor(p[g], m);
        }
        if (l31 == 0){
            #pragma unroll
            for (int g=0; g<16; g++)
                part[r0 + ROWOF(g,hi)][cs] = p[g];
        }
    }
    __syncthreads();                 // S2

    if (tid < 64){
        const float sc = 0.17677669529663688f;   // 1/sqrt(32)
        float s0 = part[tid][0]*sc, s1 = part[tid][1]*sc;
        float s2 = part[tid][2]*sc, s3 = part[tid][3]*sc;
        float mx = fmaxf(fmaxf(s0,s1),fmaxf(s2,s3));
        s0=expf(s0-mx); s1=expf(s1-mx); s2=expf(s2-mx); s3=expf(s3-mx);
        float inv = 1.0f/(s0+s1+s2+s3);
        swv[tid][0]=s0*inv; swv[tid][1]=s1*inv; swv[tid][2]=s2*inv; swv[tid][3]=s3*inv;
    }
    __syncthreads();                 // S3

    // ---- qm = swv*(v+b) ----
    f32x16 qm;
    {
        float vb_ = v_b[colg];
        #pragma unroll
        for (int g=0; g<16; g++)
            qm[g] = (av[g]+vb_) * swv[r0 + ROWOF(g,hi)][cs];
    }

    // ---- ENT: two 32-col tiles (ei strip, ej strip); A = cat(xi,xj) K=256 ----
    {
        f32x16 ae0 = Z16, ae1 = Z16;
        #pragma unroll
        for (int kc=0; kc<16; kc++){
            short8 fa = xinv[C32(r0+l31, kc*2+hi)];
            ae0 = mfma32(fa, bfrag32(wE,256,(cs<<5),kc,lane), ae0);
            ae1 = mfma32(fa, bfrag32(wE,256,128+(cs<<5),kc,lane), ae1);
        }
        float eb0 = ent_b[(cs<<5)+l31], eb1 = ent_b[128+(cs<<5)+l31];
        const int c0 = (cs<<5)+l31, c1 = 128+(cs<<5)+l31;
        #pragma unroll
        for (int g=0; g<16; g++){
            int row = r0 + ROWOF(g,hi);
            ebuf[(C32(row, c0>>3)<<3) + (c0&7)] = f2bf(ae0[g]+eb0);
            ebuf[(C32(row, c1>>3)<<3) + (c1&7)] = f2bf(ae1[g]+eb1);
        }
    }
    __syncthreads();                 // S4

    // ---- MEAS: qm += 0.25 * sum_kk (ei@Wm+b)(ej@Wm+b); ei frags cached ----
    {
        const short8* ebv = (const short8*)ebuf;
        short8 afi[8];
        #pragma unroll
        for (int kc=0; kc<8; kc++) afi[kc] = ebv[C32(r0+l31, kc*2+hi)];
        #pragma unroll 1
        for (int kk=0; kk<4; kk++){
            const short* wMk = wM + (long)kk*16384;
            f32x16 mi = Z16, mj = Z16;
            #pragma unroll
            for (int kc=0; kc<8; kc++){
                short8 bm = bfrag32(wMk,128,cs<<5,kc,lane);
                short8 afj = ebv[C32(r0+l31, 16+kc*2+hi)];
                mi = mfma32(afi[kc], bm, mi);
                mj = mfma32(afj, bm, mj);
            }
            float mb = meas_b[kk*128 + colg];
            #pragma unroll
            for (int g=0; g<16; g++)
                qm[g] += 0.25f*(mi[g]+mb)*(mj[g]+mb);
        }
    }

    // ---- write msg-in bf16 to msgb (overlays xin; xin dead since S4) ----
    #pragma unroll
    for (int g=0; g<16; g++){
        int row = r0 + ROWOF(g,hi);
        msgb[(C16(row, colg>>3)<<3) + (colg&7)] = f2bf(qm[g]);
    }
    __syncthreads();                 // S5

    // ---- OUT: msg = msgb@Wo^T + b -> msgF (overlays ebuf; dead since S5) ----
    {
        const short8* mbv = (const short8*)msgb;
        f32x16 ao = Z16;
        #pragma unroll
        for (int kc=0; kc<8; kc++){
            short8 fa = mbv[C16(r0+l31, kc*2+hi)];
            ao = mfma32(fa, bfrag32(wO,128,cs<<5,kc,lane), ao);
        }
        float ob = out_b[colg];
        #pragma unroll
        for (int g=0; g<16; g++){
            int row = r0 + ROWOF(g,hi);
            msgF[(row<<7) + (colg ^ (row&31))] = ao[g] + ob;
        }
    }
    __syncthreads();                 // S6

    // ---- per-tile segmented reduction over sorted tgt runs ----
    if (tid < 128){
        const int c = tid;
        const int tgPrev = tgPrevS, tgNext = tgNextS;
        float acc = 0.f;
        int runStart = 0;
        #pragma unroll 4
        for (int r=0; r<ET; r++){
            acc += msgF[(r<<7) + (c ^ (r&31))];
            bool last = (r==ET-1) || (tg[r+1] != tg[r]);
            if (last){
                int node = tg[r];
                if (node >= 0){
                    bool openL = (runStart==0) && (tgPrev == node);
                    bool openR = (r==ET-1)     && (tgNext == node);
                    if (openL || openR) atomicAdd(&agg[(long)node*128 + c], acc);
                    else                agg[(long)node*128 + c] = acc;
                }
                acc = 0.f; runStart = r+1;
            }
        }
    }
}

// ---------------- Stage 3: LN + exact gelu, in place on d_out ----------------
__global__ __launch_bounds__(256) void final_kernel(
    const float* __restrict__ g2, const float* __restrict__ b2,
    float* __restrict__ io)
{
    const int lane = threadIdx.x & 63;
    const int n = blockIdx.x*4 + (threadIdx.x>>6);
    float v0 = io[(long)n*128 + lane];
    float v1 = io[(long)n*128 + 64 + lane];
    float s = v0+v1, sq = v0*v0 + v1*v1;
    #pragma unroll
    for (int m=1;m<64;m<<=1){ s += __shfl_xor(s,m); sq += __shfl_xor(sq,m); }
    float mean = s*(1.0f/128.0f);
    float rstd = rsqrtf(sq*(1.0f/128.0f)-mean*mean+1e-5f);
    float y0 = (v0-mean)*rstd*g2[lane]    + b2[lane];
    float y1 = (v1-mean)*rstd*g2[64+lane] + b2[64+lane];
    io[(long)n*128+lane]    = 0.5f*y0*(1.0f+erff(y0*0.70710678118f));
    io[(long)n*128+64+lane] = 0.5f*y1*(1.0f+erff(y1*0.70710678118f));
}

extern "C" void kernel_launch(void* const* d_in, const int* in_sizes, int n_in,
                              void* d_out, int out_size, void* d_ws, size_t ws_size,
                              hipStream_t stream)
{
    const float* x      = (const float*)d_in[0];
    const int*   eidx   = (const int*)  d_in[1];
    const float* sp_w   = (const float*)d_in[2];
    const float* sp_b   = (const float*)d_in[3];
    const float* ln1_g  = (const float*)d_in[4];
    const float* ln1_b  = (const float*)d_in[5];
    const float* pg     = (const float*)d_in[6];
    const float* amp_w  = (const float*)d_in[7];
    const float* amp_b  = (const float*)d_in[8];
    const float* ph_w   = (const float*)d_in[9];
    const float* ph_b   = (const float*)d_in[10];
    const float* ent_w  = (const float*)d_in[11];
    const float* ent_b  = (const float*)d_in[12];
    const float* q_w    = (const float*)d_in[13];
    const float* q_b    = (const float*)d_in[14];
    const float* k_w    = (const float*)d_in[15];
    const float* k_b    = (const float*)d_in[16];
    const float* v_w    = (const float*)d_in[17];
    const float* v_b    = (const float*)d_in[18];
    const float* meas_w = (const float*)d_in[19];
    const float* meas_b = (const float*)d_in[20];
    const float* out_w  = (const float*)d_in[21];
    const float* out_b  = (const float*)d_in[22];
    const float* ln2_g  = (const float*)d_in[23];
    const float* ln2_b  = (const float*)d_in[24];

    char* wsb = (char*)d_ws;
    short* qfb  = (short*)wsb;                      // 25,600,000 B
    short* wAll = (short*)(wsb + 25600000);         //    442,368 B (221184 bf16)
    int* hist   = (int*)(wsb + 26042368);           //    401,408 B
    int* cnt    = (int*)(wsb + 26443776);           //    401,408 B
    int* scanv  = (int*)(wsb + 26845184);           //    401,408 B
    int* bsum   = (int*)(wsb + 27246592);           //      1,024 B
    int* boff   = (int*)(wsb + 27247616);           //      1,024 B
    int* sTgt   = (int*)(wsb + 27248640);           //  2,000,128 B
    int* sSrc   = (int*)(wsb + 29248768);           //  2,000,128 B -> 31.25 MB

    short* wE  = wAll;                              // 256*256
    short* wQ  = wE + 65536;                        // 128*128
    short* wK  = wQ + 16384;
    short* wV  = wK + 16384;
    short* wM  = wV + 16384;                        // 4*128*128
    short* wO  = wM + 65536;                        // 128*128
    short* wSP = wO + 16384;                        // 128*128
    short* wA  = wSP + 16384;                       // 64*64
    short* wP  = wA + 4096;                         // 64*64

    float* agg = (float*)d_out;

    hipMemsetAsync(d_out, 0, (size_t)NN*128*sizeof(float), stream);
    hipMemsetAsync(hist, 0, 401408, stream);
    hipMemsetAsync(cnt,  0, 401408, stream);
    hipMemsetAsync(sTgt + EE, 0xFF, (NPAD-EE)*sizeof(int), stream);   // pad tgt = -1
    hipMemsetAsync(sSrc + EE, 0x00, (NPAD-EE)*sizeof(int), stream);

    prep_kernel<<<864, 256, 0, stream>>>(ent_w, q_w, k_w, v_w, meas_w, out_w,
                                         sp_w, amp_w, ph_w, wAll);
    node_kernel<<<NNB, 512, 0, stream>>>(x, wSP, sp_b, ln1_g, ln1_b, pg,
                                         wA, amp_b, wP, ph_b, qfb);
    hist_kernel<<<(EE+255)/256, 256, 0, stream>>>(eidx, hist);
    scanA_kernel<<<196, 512, 0, stream>>>(hist, scanv, bsum);
    scanB_kernel<<<1, 256, 0, stream>>>(bsum, boff);
    scatter_kernel<<<(EE+255)/256, 256, 0, stream>>>(eidx, scanv, boff, cnt, sTgt, sSrc);
    edge_kernel<<<NEB, 512, 0, stream>>>(qfb, sTgt, sSrc,
                                         wE, ent_b, wQ, q_b, wK, k_b, wV, v_b,
                                         wM, meas_b, wO, out_b, agg);
    final_kernel<<<NN/4, 256, 0, stream>>>(ln2_g, ln2_b, agg);
}

// Round 9
// 992.980 us; speedup vs baseline: 1.1855x; 1.1855x over previous
//
#include <hip/hip_runtime.h>
#include <math.h>

#define NN 100000
#define EE 500000
#define ET 32
#define NEB  15625           // E = 32 * 15625 exactly
#define NNB  1563            // ceil(100000/64)

typedef __attribute__((ext_vector_type(8))) short short8;
typedef __attribute__((ext_vector_type(4))) float f32x4;

// LDS chunk swizzle: 16B chunks, XOR row&7 into chunk index (T2, §6 G4)
#define C32(row, ch) (((row)<<5) + ((ch) ^ ((row)&7)))           // [*][256] bf16 buffers
#define C16(row, ch) (((row)<<4) + ((ch) ^ ((row)&7)))           // [*][128] bf16 buffers
#define E16(row, col) ((C16((row),(col)>>3)<<3) + ((col)&7))

__device__ __forceinline__ f32x4 mfma16(short8 a, short8 b, f32x4 c){
    return __builtin_amdgcn_mfma_f32_16x16x32_bf16(a, b, c, 0, 0, 0);
}
__device__ __forceinline__ short f2bf(float f){
    union { float f; unsigned u; } v; v.f = f;
    unsigned r = v.u + 0x7fffu + ((v.u >> 16) & 1u);
    return (short)(r >> 16);
}
__device__ __forceinline__ float bf2f(short s){
    union { unsigned u; float f; } v; v.u = ((unsigned)(unsigned short)s) << 16;
    return v.f;
}
// B fragment 16x16x32: col=ct*16+(lane&15), k=ks*32+(lane>>4)*8
__device__ __forceinline__ short8 bfrag(const short* __restrict__ W, int K, int ct, int ks, int lane){
    return *(const short8*)(W + (long)(ct*16 + (lane&15))*K + ks*32 + (lane>>4)*8);
}

// ---------------- Prep: convert ALL stage weights to bf16 in ws ----------------
__global__ __launch_bounds__(256) void prep_kernel(
    const float* __restrict__ ent_w, const float* __restrict__ q_w,
    const float* __restrict__ k_w,   const float* __restrict__ v_w,
    const float* __restrict__ meas_w,const float* __restrict__ out_w,
    const float* __restrict__ sp_w,  const float* __restrict__ amp_w,
    const float* __restrict__ ph_w,
    short* __restrict__ dst)
{
    int i = blockIdx.x*256 + threadIdx.x;   // 221184 total
    float v;
    if      (i <  65536) v = ent_w[i];
    else if (i <  81920) v = q_w[i-65536];
    else if (i <  98304) v = k_w[i-81920];
    else if (i < 114688) v = v_w[i-98304];
    else if (i < 180224) v = meas_w[i-114688];
    else if (i < 196608) v = out_w[i-180224];
    else if (i < 212992) v = sp_w[i-196608];
    else if (i < 217088) v = amp_w[i-212992];
    else                 v = ph_w[i-217088];
    dst[i] = f2bf(v);
}

// ---------------- Sort pipeline: counting sort of edges by tgt ----------------
__global__ __launch_bounds__(256) void hist_kernel(const int* __restrict__ eidx, int* __restrict__ hist){
    int i = blockIdx.x*256 + threadIdx.x;
    if (i < EE) atomicAdd(&hist[eidx[EE+i]], 1);
}
__global__ __launch_bounds__(512) void scanA_kernel(const int* __restrict__ hist,
                                                    int* __restrict__ scanv, int* __restrict__ bsum){
    __shared__ int s[512];
    const int tid = threadIdx.x;
    const int i = blockIdx.x*512 + tid;
    int v = hist[i];
    s[tid] = v;
    __syncthreads();
    #pragma unroll
    for (int d=1; d<512; d<<=1){
        int t = (tid>=d) ? s[tid-d] : 0;
        __syncthreads();
        s[tid] += t;
        __syncthreads();
    }
    scanv[i] = s[tid] - v;
    if (tid==511) bsum[blockIdx.x] = s[511];
}
__global__ __launch_bounds__(256) void scanB_kernel(const int* __restrict__ bsum, int* __restrict__ boff){
    __shared__ int s[256];
    const int tid = threadIdx.x;
    int v = (tid<196) ? bsum[tid] : 0;
    s[tid] = v;
    __syncthreads();
    #pragma unroll
    for (int d=1; d<256; d<<=1){
        int t = (tid>=d) ? s[tid-d] : 0;
        __syncthreads();
        s[tid] += t;
        __syncthreads();
    }
    if (tid<196) boff[tid] = s[tid] - v;
}
__global__ __launch_bounds__(256) void scatter_kernel(const int* __restrict__ eidx,
    const int* __restrict__ scanv, const int* __restrict__ boff, int* __restrict__ cnt,
    int* __restrict__ sTgt, int* __restrict__ sSrc)
{
    int i = blockIdx.x*256 + threadIdx.x;
    if (i >= EE) return;
    int t = eidx[EE+i], sv = eidx[i];
    int r = atomicAdd(&cnt[t], 1);
    int pos = scanv[t] + boff[t>>9] + r;
    sTgt[pos] = t; sSrc[pos] = sv;
}

// ---------------- Stage 1: node prep via MFMA, 64 nodes/block ----------------
__global__ __launch_bounds__(512) void node_kernel(
    const float* __restrict__ x,
    const short* __restrict__ wSP, const float* __restrict__ sp_b,
    const float* __restrict__ ln1_g, const float* __restrict__ ln1_b,
    const float* __restrict__ pg,
    const short* __restrict__ wA, const float* __restrict__ amp_b,
    const short* __restrict__ wP, const float* __restrict__ ph_b,
    short* __restrict__ qfb)
{
    __shared__ short xb[64*128];
    __shared__ float yb[64*132];
    __shared__ short qsb[64*128];
    __shared__ float pgs[64];

    const int tid = threadIdx.x;
    const int lane = tid & 63;
    const int w    = tid >> 6;
    const int l15  = lane & 15;
    const int lj   = (lane >> 4) << 2;
    const int n0   = blockIdx.x * 64;

    if (tid < 64){
        float s = 0.f;
        #pragma unroll
        for (int r=0;r<8;r++) s += pg[r*64 + tid];
        pgs[tid] = s;
    }
    for (int t = tid; t < 1024; t += 512){
        int e = t >> 4, c8 = t & 15;
        int n = n0 + e; if (n >= NN) n = NN-1;
        const float4* xg = (const float4*)(x + (long)n*128 + c8*8);
        float4 a = xg[0], b = xg[1];
        short8 sv;
        sv[0]=f2bf(a.x); sv[1]=f2bf(a.y); sv[2]=f2bf(a.z); sv[3]=f2bf(a.w);
        sv[4]=f2bf(b.x); sv[5]=f2bf(b.y); sv[6]=f2bf(b.z); sv[7]=f2bf(b.w);
        ((short8*)xb)[C16(e, c8)] = sv;
    }
    __syncthreads();

    const short8* xbv = (const short8*)xb;
    const int col = (w<<4) + l15;

    {
        f32x4 acc[4];
        #pragma unroll
        for (int r=0;r<4;r++) acc[r]=(f32x4){0,0,0,0};
        #pragma unroll
        for (int ks=0; ks<4; ks++){
            short8 bw = bfrag(wSP,128,w,ks,lane);
            #pragma unroll
            for (int r=0;r<4;r++){
                int row = r*16+l15;
                acc[r] = mfma16(xbv[(row<<4) + (((ks<<2)+(lane>>4)) ^ (row&7))], bw, acc[r]);
            }
        }
        float bias = sp_b[col];
        #pragma unroll
        for (int r=0;r<4;r++){
            #pragma unroll
            for (int j=0;j<4;j++)
                yb[(r*16+lj+j)*132 + col] = acc[r][j] + bias;
        }
    }
    __syncthreads();

    {
        const int row = tid >> 3, cs = tid & 7;
        float v[16];
        float s = 0.f, sq = 0.f;
        #pragma unroll
        for (int i=0;i<16;i++){
            v[i] = yb[row*132 + cs*16 + i];
            s += v[i]; sq += v[i]*v[i];
        }
        #pragma unroll
        for (int m=1;m<8;m<<=1){ s += __shfl_xor(s,m); sq += __shfl_xor(sq,m); }
        float mean = s*(1.0f/128.0f);
        float rstd = rsqrtf(sq*(1.0f/128.0f) - mean*mean + 1e-5f);
        short8 s0, s1;
        #pragma unroll
        for (int i=0;i<16;i++){
            int c = cs*16 + i;
            float q = tanhf((v[i]-mean)*rstd*ln1_g[c] + ln1_b[c]);
            if (i<8) s0[i] = f2bf(q); else s1[i-8] = f2bf(q);
        }
        ((short8*)qsb)[C16(row, cs*2  )] = s0;
        ((short8*)qsb)[C16(row, cs*2+1)] = s1;
    }
    __syncthreads();

    {
        const short8* qv = (const short8*)qsb;
        const int isPh = w >> 2;
        const int ct   = w & 3;
        f32x4 a4[4];
        #pragma unroll
        for (int r=0;r<4;r++) a4[r]=(f32x4){0,0,0,0};
        #pragma unroll
        for (int ks=0; ks<2; ks++){
            short8 bw = bfrag(isPh ? wP : wA, 64, ct, ks, lane);
            #pragma unroll
            for (int r=0;r<4;r++){
                int row = r*16+l15;
                int ch = isPh*8 + (ks<<2)+(lane>>4);
                a4[r] = mfma16(qv[(row<<4) + (ch ^ (row&7))], bw, a4[r]);
            }
        }
        const int oc = ct*16 + l15;
        float bs = isPh ? ph_b[oc] : amp_b[oc];
        #pragma unroll
        for (int r=0;r<4;r++){
            #pragma unroll
            for (int j=0;j<4;j++){
                float vv = a4[r][j] + bs;
                float ov = isPh ? tanhf(vv)*3.14159265358979323846f
                                : 1.0f/(1.0f+expf(-vv));
                yb[(r*16+lj+j)*132 + isPh*64 + oc] = ov;
            }
        }
    }
    __syncthreads();

    {
        const int row = tid >> 3, cs = tid & 7;
        const int n = n0 + row;
        short8 outc, outs;
        #pragma unroll
        for (int i=0;i<8;i++){
            int c = cs*8 + i;
            float amp  = yb[row*132 + c];
            float ph   = yb[row*132 + 64 + c];
            float real = bf2f(qsb[E16(row, c)]);
            float ang  = ph + real*pgs[c];
            outc[i] = f2bf(amp * cosf(ang));
            outs[i] = f2bf(amp * sinf(ang));
        }
        if (n < NN){
            *(short8*)(qfb + (long)n*128 + cs*8)      = outc;
            *(short8*)(qfb + (long)n*128 + 64 + cs*8) = outs;
        }
    }
}

// ---------------- Stage 2: 32 edges / 256 threads / 4 waves; wave w = head w (cols 32w..32w+31) ----------------
__global__ __launch_bounds__(256) void edge_kernel(
    const short* __restrict__ qfb,
    const int* __restrict__ sTgt, const int* __restrict__ sSrc,
    const short* __restrict__ wE, const float* __restrict__ ent_b,
    const short* __restrict__ wQ, const float* __restrict__ q_b,
    const short* __restrict__ wK, const float* __restrict__ k_b,
    const short* __restrict__ wV, const float* __restrict__ v_b,
    const short* __restrict__ wM, const float* __restrict__ meas_b,
    const short* __restrict__ wO, const float* __restrict__ out_b,
    float* __restrict__ agg)
{
    __shared__ short xin[ET*256];                 // 16 KB [xi|xj] C32; msgb bf16 [32][128] overlays after ENT
    __shared__ __align__(16) char bufB[ET*132*4]; // 16.9 KB: ebuf bf16 [32][256] C32; msgF f32 stride 132 overlays
    __shared__ float part[ET][5];
    __shared__ float swv[ET][5];
    __shared__ int tg[ET], srr[ET];
    __shared__ int tgPrevS, tgNextS;

    short* msgb = xin;
    short* ebuf = (short*)bufB;
    float* msgF = (float*)bufB;

    // bijective XCD-chunked swizzle (m204)
    const int nwg = gridDim.x, orig = blockIdx.x;
    const int qd = nwg>>3, rm = nwg&7, xc = orig&7, oo = orig>>3;
    const int bid = (xc<rm ? xc*(qd+1) : rm*(qd+1)+(xc-rm)*qd) + oo;

    const int tid  = threadIdx.x;
    const int lane = tid & 63;
    const int w    = tid >> 6;          // wave 0..3  == head
    const long e0  = (long)bid * ET;
    const int l15  = lane & 15;
    const int lj   = (lane >> 4) << 2;
    const int ct0  = 2*w, ct1 = 2*w+1;  // two 16-col tiles = head w's 32 cols
    const int c0   = ct0*16 + l15, c1 = ct1*16 + l15;

    if (tid < ET) { tg[tid] = sTgt[e0+tid]; srr[tid] = sSrc[e0+tid]; }
    if (tid == 32) tgPrevS = (e0 > 0)     ? sTgt[e0-1]  : -2;
    if (tid == 33) tgNextS = (e0+ET < EE) ? sTgt[e0+ET] : -2;
    __syncthreads();                    // S0

    for (int t = tid; t < ET*32; t += 256) {
        int e = t >> 5, c8 = t & 31;
        int node = (c8 < 16) ? tg[e] : srr[e];
        short8 val = ((const short8*)(qfb + (long)node*128))[c8 & 15];
        ((short8*)xin)[C32(e, c8)] = val;
    }
    __syncthreads();                    // S1

    const short8* xinv = (const short8*)xin;

    // ---- Q,K for head w; scores fully in-register (16-lane shfl reduce) ----
    {
        f32x4 aq[2][2], ak[2][2];
        #pragma unroll
        for (int r=0;r<2;r++){
            aq[r][0]=(f32x4){0,0,0,0}; aq[r][1]=(f32x4){0,0,0,0};
            ak[r][0]=(f32x4){0,0,0,0}; ak[r][1]=(f32x4){0,0,0,0};
        }
        #pragma unroll
        for (int ks=0; ks<4; ks++){
            short8 bq0 = bfrag(wQ,128,ct0,ks,lane);
            short8 bq1 = bfrag(wQ,128,ct1,ks,lane);
            short8 bk0 = bfrag(wK,128,ct0,ks,lane);
            short8 bk1 = bfrag(wK,128,ct1,ks,lane);
            #pragma unroll
            for (int r=0;r<2;r++){
                short8 ai = xinv[C32(r*16+l15, (ks<<2)+(lane>>4))];
                short8 aj = xinv[C32(r*16+l15, 16+(ks<<2)+(lane>>4))];
                aq[r][0] = mfma16(ai, bq0, aq[r][0]);
                aq[r][1] = mfma16(ai, bq1, aq[r][1]);
                ak[r][0] = mfma16(aj, bk0, ak[r][0]);
                ak[r][1] = mfma16(aj, bk1, ak[r][1]);
            }
        }
        float qb0 = q_b[c0], qb1 = q_b[c1], kb0 = k_b[c0], kb1 = k_b[c1];
        float p[2][4];
        #pragma unroll
        for (int r=0;r<2;r++){
            #pragma unroll
            for (int j=0;j<4;j++)
                p[r][j] = (aq[r][0][j]+qb0)*(ak[r][0][j]+kb0)
                        + (aq[r][1][j]+qb1)*(ak[r][1][j]+kb1);
        }
        #pragma unroll
        for (int m=1;m<16;m<<=1){
            #pragma unroll
            for (int r=0;r<2;r++){
                #pragma unroll
                for (int j=0;j<4;j++)
                    p[r][j] += __shfl_xor(p[r][j], m);
            }
        }
        if (l15 == 0){
            #pragma unroll
            for (int r=0;r<2;r++){
                #pragma unroll
                for (int j=0;j<4;j++)
                    part[r*16+lj+j][w] = p[r][j];
            }
        }
    }
    __syncthreads();                    // S2

    // ---- softmax (tid<32) concurrent with V MFMAs (all threads) ----
    if (tid < ET){
        const float sc = 0.17677669529663688f;   // 1/sqrt(32)
        float s0 = part[tid][0]*sc, s1 = part[tid][1]*sc;
        float s2 = part[tid][2]*sc, s3 = part[tid][3]*sc;
        float mx = fmaxf(fmaxf(s0,s1),fmaxf(s2,s3));
        s0=expf(s0-mx); s1=expf(s1-mx); s2=expf(s2-mx); s3=expf(s3-mx);
        float inv = 1.0f/(s0+s1+s2+s3);
        swv[tid][0]=s0*inv; swv[tid][1]=s1*inv; swv[tid][2]=s2*inv; swv[tid][3]=s3*inv;
    }
    f32x4 av[2][2];
    {
        #pragma unroll
        for (int r=0;r<2;r++){ av[r][0]=(f32x4){0,0,0,0}; av[r][1]=(f32x4){0,0,0,0}; }
        #pragma unroll
        for (int ks=0; ks<4; ks++){
            short8 bv0 = bfrag(wV,128,ct0,ks,lane);
            short8 bv1 = bfrag(wV,128,ct1,ks,lane);
            #pragma unroll
            for (int r=0;r<2;r++){
                short8 aj = xinv[C32(r*16+l15, 16+(ks<<2)+(lane>>4))];
                av[r][0] = mfma16(aj, bv0, av[r][0]);
                av[r][1] = mfma16(aj, bv1, av[r][1]);
            }
        }
    }
    __syncthreads();                    // S3

    f32x4 qm[2][2];
    {
        float vb0 = v_b[c0], vb1 = v_b[c1];
        #pragma unroll
        for (int r=0;r<2;r++){
            #pragma unroll
            for (int j=0;j<4;j++){
                float sw = swv[r*16+lj+j][w];
                qm[r][0][j] = (av[r][0][j] + vb0) * sw;
                qm[r][1][j] = (av[r][1][j] + vb1) * sw;
            }
        }
    }

    // ---- ENT: 4 col-tiles per wave (ct = 4w+t), A = cat(xi,xj), K=256 -> ebuf ----
    #pragma unroll 1
    for (int t=0; t<4; t++){
        const int ct = 4*w + t;
        f32x4 ae[2];
        ae[0]=(f32x4){0,0,0,0}; ae[1]=(f32x4){0,0,0,0};
        #pragma unroll
        for (int ks=0; ks<8; ks++){
            short8 b0 = bfrag(wE,256,ct,ks,lane);
            #pragma unroll
            for (int r=0;r<2;r++)
                ae[r] = mfma16(xinv[C32(r*16+l15, (ks<<2)+(lane>>4))], b0, ae[r]);
        }
        float bb = ent_b[ct*16 + l15];
        const int cc = ct*16 + l15;
        #pragma unroll
        for (int r=0;r<2;r++){
            #pragma unroll
            for (int j=0;j<4;j++)
                ebuf[(C32(r*16+lj+j, cc>>3)<<3) + (cc&7)] = f2bf(ae[r][j] + bb);
        }
    }
    __syncthreads();                    // S4  (xin dead after this point)

    // ---- MEAS: qm += 0.25 * sum_kk (ei@Wm+b)(ej@Wm+b) ----
    {
        const short8* ebv = (const short8*)ebuf;
        #pragma unroll 1
        for (int kk=0; kk<4; kk++){
            const short* wMk = wM + (long)kk*16384;
            #pragma unroll
            for (int ci=0; ci<2; ci++){
                const int ct = 2*w + ci;
                short8 bm[4];
                #pragma unroll
                for (int ks=0;ks<4;ks++) bm[ks] = bfrag(wMk, 128, ct, ks, lane);
                float mb = meas_b[kk*128 + ct*16 + l15];
                #pragma unroll
                for (int r=0;r<2;r++){
                    f32x4 mi=(f32x4){0,0,0,0}, mj=(f32x4){0,0,0,0};
                    #pragma unroll
                    for (int ks=0;ks<4;ks++)
                        mi = mfma16(ebv[C32(r*16+l15, (ks<<2)+(lane>>4))], bm[ks], mi);
                    #pragma unroll
                    for (int ks=0;ks<4;ks++)
                        mj = mfma16(ebv[C32(r*16+l15, 16+(ks<<2)+(lane>>4))], bm[ks], mj);
                    #pragma unroll
                    for (int j=0;j<4;j++)
                        qm[r][ci][j] += 0.25f*(mi[j]+mb)*(mj[j]+mb);
                }
            }
        }
    }
    // ---- write msg-in bf16 to msgb (overlays xin) ----
    {
        #pragma unroll
        for (int r=0;r<2;r++){
            #pragma unroll
            for (int ci=0; ci<2; ci++){
                const int cc = (2*w+ci)*16 + l15;
                #pragma unroll
                for (int j=0;j<4;j++){
                    int row = r*16 + lj + j;
                    msgb[(C16(row, cc>>3)<<3) + (cc&7)] = f2bf(qm[r][ci][j]);
                }
            }
        }
    }
    __syncthreads();                    // S5  (ebuf dead after this point)

    // ---- OUT: msg = msgb@Wo^T + b -> msgF (f32, stride 132, overlays ebuf) ----
    {
        const short8* mbv = (const short8*)msgb;
        f32x4 ao[2][2];
        #pragma unroll
        for (int r=0;r<2;r++){ ao[r][0]=(f32x4){0,0,0,0}; ao[r][1]=(f32x4){0,0,0,0}; }
        #pragma unroll
        for (int ks=0; ks<4; ks++){
            short8 bo0 = bfrag(wO,128,ct0,ks,lane);
            short8 bo1 = bfrag(wO,128,ct1,ks,lane);
            #pragma unroll
            for (int r=0;r<2;r++){
                short8 fa = mbv[C16(r*16+l15, (ks<<2)+(lane>>4))];
                ao[r][0] = mfma16(fa, bo0, ao[r][0]);
                ao[r][1] = mfma16(fa, bo1, ao[r][1]);
            }
        }
        float ob0 = out_b[c0], ob1 = out_b[c1];
        #pragma unroll
        for (int r=0;r<2;r++){
            #pragma unroll
            for (int j=0;j<4;j++){
                int row = r*16 + lj + j;
                msgF[row*132 + c0] = ao[r][0][j] + ob0;
                msgF[row*132 + c1] = ao[r][1][j] + ob1;
            }
        }
    }
    __syncthreads();                    // S6

    // ---- per-tile segmented reduction over sorted tgt runs ----
    if (tid < 128){
        const int c = tid;
        const int tgPrev = tgPrevS, tgNext = tgNextS;
        float acc = 0.f;
        int runStart = 0;
        #pragma unroll 4
        for (int r=0; r<ET; r++){
            acc += msgF[r*132 + c];
            bool last = (r==ET-1) || (tg[r+1] != tg[r]);
            if (last){
                int node = tg[r];
                bool openL = (runStart==0) && (tgPrev == node);
                bool openR = (r==ET-1)     && (tgNext == node);
                if (openL || openR) atomicAdd(&agg[(long)node*128 + c], acc);
                else                agg[(long)node*128 + c] = acc;
                acc = 0.f; runStart = r+1;
            }
        }
    }
}

// ---------------- Stage 3: LN + exact gelu, in place on d_out ----------------
__global__ __launch_bounds__(256) void final_kernel(
    const float* __restrict__ g2, const float* __restrict__ b2,
    float* __restrict__ io)
{
    const int lane = threadIdx.x & 63;
    const int n = blockIdx.x*4 + (threadIdx.x>>6);
    float v0 = io[(long)n*128 + lane];
    float v1 = io[(long)n*128 + 64 + lane];
    float s = v0+v1, sq = v0*v0 + v1*v1;
    #pragma unroll
    for (int m=1;m<64;m<<=1){ s += __shfl_xor(s,m); sq += __shfl_xor(sq,m); }
    float mean = s*(1.0f/128.0f);
    float rstd = rsqrtf(sq*(1.0f/128.0f)-mean*mean+1e-5f);
    float y0 = (v0-mean)*rstd*g2[lane]    + b2[lane];
    float y1 = (v1-mean)*rstd*g2[64+lane] + b2[64+lane];
    io[(long)n*128+lane]    = 0.5f*y0*(1.0f+erff(y0*0.70710678118f));
    io[(long)n*128+64+lane] = 0.5f*y1*(1.0f+erff(y1*0.70710678118f));
}

extern "C" void kernel_launch(void* const* d_in, const int* in_sizes, int n_in,
                              void* d_out, int out_size, void* d_ws, size_t ws_size,
                              hipStream_t stream)
{
    const float* x      = (const float*)d_in[0];
    const int*   eidx   = (const int*)  d_in[1];
    const float* sp_w   = (const float*)d_in[2];
    const float* sp_b   = (const float*)d_in[3];
    const float* ln1_g  = (const float*)d_in[4];
    const float* ln1_b  = (const float*)d_in[5];
    const float* pg     = (const float*)d_in[6];
    const float* amp_w  = (const float*)d_in[7];
    const float* amp_b  = (const float*)d_in[8];
    const float* ph_w   = (const float*)d_in[9];
    const float* ph_b   = (const float*)d_in[10];
    const float* ent_w  = (const float*)d_in[11];
    const float* ent_b  = (const float*)d_in[12];
    const float* q_w    = (const float*)d_in[13];
    const float* q_b    = (const float*)d_in[14];
    const float* k_w    = (const float*)d_in[15];
    const float* k_b    = (const float*)d_in[16];
    const float* v_w    = (const float*)d_in[17];
    const float* v_b    = (const float*)d_in[18];
    const float* meas_w = (const float*)d_in[19];
    const float* meas_b = (const float*)d_in[20];
    const float* out_w  = (const float*)d_in[21];
    const float* out_b  = (const float*)d_in[22];
    const float* ln2_g  = (const float*)d_in[23];
    const float* ln2_b  = (const float*)d_in[24];

    char* wsb = (char*)d_ws;
    short* qfb  = (short*)wsb;                      // 25,600,000 B
    short* wAll = (short*)(wsb + 25600000);         //    442,368 B (221184 bf16)
    int* hist   = (int*)(wsb + 26042368);           //    401,408 B
    int* cnt    = (int*)(wsb + 26443776);           //    401,408 B
    int* scanv  = (int*)(wsb + 26845184);           //    401,408 B
    int* bsum   = (int*)(wsb + 27246592);           //      1,024 B
    int* boff   = (int*)(wsb + 27247616);           //      1,024 B
    int* sTgt   = (int*)(wsb + 27248640);           //  2,000,000 B
    int* sSrc   = (int*)(wsb + 29248640);           //  2,000,000 B -> 31.25 MB

    short* wE  = wAll;                              // 256*256
    short* wQ  = wE + 65536;                        // 128*128
    short* wK  = wQ + 16384;
    short* wV  = wK + 16384;
    short* wM  = wV + 16384;                        // 4*128*128
    short* wO  = wM + 65536;                        // 128*128
    short* wSP = wO + 16384;                        // 128*128
    short* wA  = wSP + 16384;                       // 64*64
    short* wP  = wA + 4096;                         // 64*64

    float* agg = (float*)d_out;

    hipMemsetAsync(d_out, 0, (size_t)NN*128*sizeof(float), stream);
    hipMemsetAsync(hist, 0, 401408, stream);
    hipMemsetAsync(cnt,  0, 401408, stream);

    prep_kernel<<<864, 256, 0, stream>>>(ent_w, q_w, k_w, v_w, meas_w, out_w,
                                         sp_w, amp_w, ph_w, wAll);
    node_kernel<<<NNB, 512, 0, stream>>>(x, wSP, sp_b, ln1_g, ln1_b, pg,
                                         wA, amp_b, wP, ph_b, qfb);
    hist_kernel<<<(EE+255)/256, 256, 0, stream>>>(eidx, hist);
    scanA_kernel<<<196, 512, 0, stream>>>(hist, scanv, bsum);
    scanB_kernel<<<1, 256, 0, stream>>>(bsum, boff);
    scatter_kernel<<<(EE+255)/256, 256, 0, stream>>>(eidx, scanv, boff, cnt, sTgt, sSrc);
    edge_kernel<<<NEB, 256, 0, stream>>>(qfb, sTgt, sSrc,
                                         wE, ent_b, wQ, q_b, wK, k_b, wV, v_b,
                                         wM, meas_b, wO, out_b, agg);
    final_kernel<<<NN/4, 256, 0, stream>>>(ln2_g, ln2_b, agg);
}

// Round 10
// 980.001 us; speedup vs baseline: 1.2012x; 1.0132x over previous
//
#include <hip/hip_runtime.h>
#include <math.h>

#define NN 100000
#define EE 500000
#define ET 32
#define NEB  15625           // E = 32 * 15625 exactly
#define NNB  1563            // ceil(100000/64)

typedef __attribute__((ext_vector_type(8))) short short8;
typedef __attribute__((ext_vector_type(4))) float f32x4;

// LDS chunk swizzle: 16B chunks, XOR row&7 into chunk index (T2, §6 G4)
#define C32(row, ch) (((row)<<5) + ((ch) ^ ((row)&7)))           // [*][256] bf16 buffers
#define C16(row, ch) (((row)<<4) + ((ch) ^ ((row)&7)))           // [*][128] bf16 buffers
#define E16(row, col) ((C16((row),(col)>>3)<<3) + ((col)&7))

__device__ __forceinline__ f32x4 mfma16(short8 a, short8 b, f32x4 c){
    return __builtin_amdgcn_mfma_f32_16x16x32_bf16(a, b, c, 0, 0, 0);
}
__device__ __forceinline__ short f2bf(float f){
    union { float f; unsigned u; } v; v.f = f;
    unsigned r = v.u + 0x7fffu + ((v.u >> 16) & 1u);
    return (short)(r >> 16);
}
__device__ __forceinline__ float bf2f(short s){
    union { unsigned u; float f; } v; v.u = ((unsigned)(unsigned short)s) << 16;
    return v.f;
}
// B fragment 16x16x32: col=ct*16+(lane&15), k=ks*32+(lane>>4)*8
__device__ __forceinline__ short8 bfrag(const short* __restrict__ W, int K, int ct, int ks, int lane){
    return *(const short8*)(W + (long)(ct*16 + (lane&15))*K + ks*32 + (lane>>4)*8);
}

// ---------------- Prep: convert ALL stage weights to bf16 in ws ----------------
__global__ __launch_bounds__(256) void prep_kernel(
    const float* __restrict__ ent_w, const float* __restrict__ q_w,
    const float* __restrict__ k_w,   const float* __restrict__ v_w,
    const float* __restrict__ meas_w,const float* __restrict__ out_w,
    const float* __restrict__ sp_w,  const float* __restrict__ amp_w,
    const float* __restrict__ ph_w,
    short* __restrict__ dst)
{
    int i = blockIdx.x*256 + threadIdx.x;   // 221184 total
    float v;
    if      (i <  65536) v = ent_w[i];
    else if (i <  81920) v = q_w[i-65536];
    else if (i <  98304) v = k_w[i-81920];
    else if (i < 114688) v = v_w[i-98304];
    else if (i < 180224) v = meas_w[i-114688];
    else if (i < 196608) v = out_w[i-180224];
    else if (i < 212992) v = sp_w[i-196608];
    else if (i < 217088) v = amp_w[i-212992];
    else                 v = ph_w[i-217088];
    dst[i] = f2bf(v);
}

// ---------------- Sort pipeline: counting sort of edges by tgt ----------------
__global__ __launch_bounds__(256) void hist_kernel(const int* __restrict__ eidx, int* __restrict__ hist){
    int i = blockIdx.x*256 + threadIdx.x;
    if (i < EE) atomicAdd(&hist[eidx[EE+i]], 1);
}
__global__ __launch_bounds__(512) void scanA_kernel(const int* __restrict__ hist,
                                                    int* __restrict__ scanv, int* __restrict__ bsum){
    __shared__ int s[512];
    const int tid = threadIdx.x;
    const int i = blockIdx.x*512 + tid;
    int v = hist[i];
    s[tid] = v;
    __syncthreads();
    #pragma unroll
    for (int d=1; d<512; d<<=1){
        int t = (tid>=d) ? s[tid-d] : 0;
        __syncthreads();
        s[tid] += t;
        __syncthreads();
    }
    scanv[i] = s[tid] - v;
    if (tid==511) bsum[blockIdx.x] = s[511];
}
__global__ __launch_bounds__(256) void scanB_kernel(const int* __restrict__ bsum, int* __restrict__ boff){
    __shared__ int s[256];
    const int tid = threadIdx.x;
    int v = (tid<196) ? bsum[tid] : 0;
    s[tid] = v;
    __syncthreads();
    #pragma unroll
    for (int d=1; d<256; d<<=1){
        int t = (tid>=d) ? s[tid-d] : 0;
        __syncthreads();
        s[tid] += t;
        __syncthreads();
    }
    if (tid<196) boff[tid] = s[tid] - v;
}
__global__ __launch_bounds__(256) void scatter_kernel(const int* __restrict__ eidx,
    const int* __restrict__ scanv, const int* __restrict__ boff, int* __restrict__ cnt,
    int* __restrict__ sTgt, int* __restrict__ sSrc)
{
    int i = blockIdx.x*256 + threadIdx.x;
    if (i >= EE) return;
    int t = eidx[EE+i], sv = eidx[i];
    int r = atomicAdd(&cnt[t], 1);
    int pos = scanv[t] + boff[t>>9] + r;
    sTgt[pos] = t; sSrc[pos] = sv;
}

// ---------------- Stage 1: node prep via MFMA, 64 nodes/block ----------------
__global__ __launch_bounds__(512) void node_kernel(
    const float* __restrict__ x,
    const short* __restrict__ wSP, const float* __restrict__ sp_b,
    const float* __restrict__ ln1_g, const float* __restrict__ ln1_b,
    const float* __restrict__ pg,
    const short* __restrict__ wA, const float* __restrict__ amp_b,
    const short* __restrict__ wP, const float* __restrict__ ph_b,
    short* __restrict__ qfb)
{
    __shared__ short xb[64*128];
    __shared__ float yb[64*132];
    __shared__ short qsb[64*128];
    __shared__ float pgs[64];

    const int tid = threadIdx.x;
    const int lane = tid & 63;
    const int w    = tid >> 6;
    const int l15  = lane & 15;
    const int lj   = (lane >> 4) << 2;
    const int n0   = blockIdx.x * 64;

    if (tid < 64){
        float s = 0.f;
        #pragma unroll
        for (int r=0;r<8;r++) s += pg[r*64 + tid];
        pgs[tid] = s;
    }
    for (int t = tid; t < 1024; t += 512){
        int e = t >> 4, c8 = t & 15;
        int n = n0 + e; if (n >= NN) n = NN-1;
        const float4* xg = (const float4*)(x + (long)n*128 + c8*8);
        float4 a = xg[0], b = xg[1];
        short8 sv;
        sv[0]=f2bf(a.x); sv[1]=f2bf(a.y); sv[2]=f2bf(a.z); sv[3]=f2bf(a.w);
        sv[4]=f2bf(b.x); sv[5]=f2bf(b.y); sv[6]=f2bf(b.z); sv[7]=f2bf(b.w);
        ((short8*)xb)[C16(e, c8)] = sv;
    }
    __syncthreads();

    const short8* xbv = (const short8*)xb;
    const int col = (w<<4) + l15;

    {
        f32x4 acc[4];
        #pragma unroll
        for (int r=0;r<4;r++) acc[r]=(f32x4){0,0,0,0};
        #pragma unroll
        for (int ks=0; ks<4; ks++){
            short8 bw = bfrag(wSP,128,w,ks,lane);
            #pragma unroll
            for (int r=0;r<4;r++){
                int row = r*16+l15;
                acc[r] = mfma16(xbv[(row<<4) + (((ks<<2)+(lane>>4)) ^ (row&7))], bw, acc[r]);
            }
        }
        float bias = sp_b[col];
        #pragma unroll
        for (int r=0;r<4;r++){
            #pragma unroll
            for (int j=0;j<4;j++)
                yb[(r*16+lj+j)*132 + col] = acc[r][j] + bias;
        }
    }
    __syncthreads();

    {
        const int row = tid >> 3, cs = tid & 7;
        float v[16];
        float s = 0.f, sq = 0.f;
        #pragma unroll
        for (int i=0;i<16;i++){
            v[i] = yb[row*132 + cs*16 + i];
            s += v[i]; sq += v[i]*v[i];
        }
        #pragma unroll
        for (int m=1;m<8;m<<=1){ s += __shfl_xor(s,m); sq += __shfl_xor(sq,m); }
        float mean = s*(1.0f/128.0f);
        float rstd = rsqrtf(sq*(1.0f/128.0f) - mean*mean + 1e-5f);
        short8 s0, s1;
        #pragma unroll
        for (int i=0;i<16;i++){
            int c = cs*16 + i;
            float q = tanhf((v[i]-mean)*rstd*ln1_g[c] + ln1_b[c]);
            if (i<8) s0[i] = f2bf(q); else s1[i-8] = f2bf(q);
        }
        ((short8*)qsb)[C16(row, cs*2  )] = s0;
        ((short8*)qsb)[C16(row, cs*2+1)] = s1;
    }
    __syncthreads();

    {
        const short8* qv = (const short8*)qsb;
        const int isPh = w >> 2;
        const int ct   = w & 3;
        f32x4 a4[4];
        #pragma unroll
        for (int r=0;r<4;r++) a4[r]=(f32x4){0,0,0,0};
        #pragma unroll
        for (int ks=0; ks<2; ks++){
            short8 bw = bfrag(isPh ? wP : wA, 64, ct, ks, lane);
            #pragma unroll
            for (int r=0;r<4;r++){
                int row = r*16+l15;
                int ch = isPh*8 + (ks<<2)+(lane>>4);
                a4[r] = mfma16(qv[(row<<4) + (ch ^ (row&7))], bw, a4[r]);
            }
        }
        const int oc = ct*16 + l15;
        float bs = isPh ? ph_b[oc] : amp_b[oc];
        #pragma unroll
        for (int r=0;r<4;r++){
            #pragma unroll
            for (int j=0;j<4;j++){
                float vv = a4[r][j] + bs;
                float ov = isPh ? tanhf(vv)*3.14159265358979323846f
                                : 1.0f/(1.0f+expf(-vv));
                yb[(r*16+lj+j)*132 + isPh*64 + oc] = ov;
            }
        }
    }
    __syncthreads();

    {
        const int row = tid >> 3, cs = tid & 7;
        const int n = n0 + row;
        short8 outc, outs;
        #pragma unroll
        for (int i=0;i<8;i++){
            int c = cs*8 + i;
            float amp  = yb[row*132 + c];
            float ph   = yb[row*132 + 64 + c];
            float real = bf2f(qsb[E16(row, c)]);
            float ang  = ph + real*pgs[c];
            outc[i] = f2bf(amp * cosf(ang));
            outs[i] = f2bf(amp * sinf(ang));
        }
        if (n < NN){
            *(short8*)(qfb + (long)n*128 + cs*8)      = outc;
            *(short8*)(qfb + (long)n*128 + 64 + cs*8) = outs;
        }
    }
}

// ---------------- Stage 2: 32 edges / 256 threads / 4 waves; A-frags register-cached ----------------
// Frag convention per lane: F0[ks]/F1[ks] (ks 0..7) = cat-row chunk (ks<<2)+(lane>>4) of row {0,1}*16+l15.
// ks 0..3 -> xi (cols 0..127), ks 4..7 -> xj (cols 128..255). Same for E (ent output).
__global__ __launch_bounds__(256) void edge_kernel(
    const short* __restrict__ qfb,
    const int* __restrict__ sTgt, const int* __restrict__ sSrc,
    const short* __restrict__ wE, const float* __restrict__ ent_b,
    const short* __restrict__ wQ, const float* __restrict__ q_b,
    const short* __restrict__ wK, const float* __restrict__ k_b,
    const short* __restrict__ wV, const float* __restrict__ v_b,
    const short* __restrict__ wM, const float* __restrict__ meas_b,
    const short* __restrict__ wO, const float* __restrict__ out_b,
    float* __restrict__ agg)
{
    __shared__ short xin[ET*256];                 // 16 KB [xi|xj] C32; msgb bf16 [32][128] overlays
    __shared__ __align__(16) char bufB[ET*132*4]; // 16.9 KB: ebuf bf16 [32][256] C32; msgF f32 stride 132 overlays
    __shared__ float part[ET][5];
    __shared__ float swv[ET][5];
    __shared__ int tg[ET], srr[ET];
    __shared__ int tgPrevS, tgNextS;

    short* msgb = xin;
    short* ebuf = (short*)bufB;
    float* msgF = (float*)bufB;

    // bijective XCD-chunked swizzle (m204)
    const int nwg = gridDim.x, orig = blockIdx.x;
    const int qd = nwg>>3, rm = nwg&7, xc = orig&7, oo = orig>>3;
    const int bid = (xc<rm ? xc*(qd+1) : rm*(qd+1)+(xc-rm)*qd) + oo;

    const int tid  = threadIdx.x;
    const int lane = tid & 63;
    const int w    = tid >> 6;          // wave 0..3  == head
    const long e0  = (long)bid * ET;
    const int l15  = lane & 15;
    const int lh   = lane >> 4;         // 0..3
    const int lj   = lh << 2;
    const int ct0  = 2*w, ct1 = 2*w+1;
    const int c0   = ct0*16 + l15, c1 = ct1*16 + l15;

    if (tid < ET) { tg[tid] = sTgt[e0+tid]; srr[tid] = sSrc[e0+tid]; }
    if (tid == 32) tgPrevS = (e0 > 0)     ? sTgt[e0-1]  : -2;
    if (tid == 33) tgNextS = (e0+ET < EE) ? sTgt[e0+ET] : -2;
    __syncthreads();                    // S0

    for (int t = tid; t < ET*32; t += 256) {
        int e = t >> 5, c8 = t & 31;
        int node = (c8 < 16) ? tg[e] : srr[e];
        short8 val = ((const short8*)(qfb + (long)node*128))[c8 & 15];
        ((short8*)xin)[C32(e, c8)] = val;
    }
    __syncthreads();                    // S1

    const short8* xinv = (const short8*)xin;

    // ---- load ALL A-frags once (16 ds_read_b128); xin LDS dead afterwards ----
    short8 F0[8], F1[8];
    #pragma unroll
    for (int ks=0; ks<8; ks++){
        F0[ks] = xinv[C32(l15,      (ks<<2)+lh)];
        F1[ks] = xinv[C32(16+l15,   (ks<<2)+lh)];
    }

    // ---- Q,K (regs); scores fully in-register (16-lane shfl reduce) ----
    {
        f32x4 aq0[2], aq1[2], ak0[2], ak1[2];
        #pragma unroll
        for (int r=0;r<2;r++){ aq0[r]=(f32x4){0,0,0,0}; aq1[r]=(f32x4){0,0,0,0};
                               ak0[r]=(f32x4){0,0,0,0}; ak1[r]=(f32x4){0,0,0,0}; }
        #pragma unroll
        for (int ks=0; ks<4; ks++){
            short8 bq0 = bfrag(wQ,128,ct0,ks,lane);
            short8 bq1 = bfrag(wQ,128,ct1,ks,lane);
            short8 bk0 = bfrag(wK,128,ct0,ks,lane);
            short8 bk1 = bfrag(wK,128,ct1,ks,lane);
            aq0[0] = mfma16(F0[ks],   bq0, aq0[0]);  aq0[1] = mfma16(F1[ks],   bq0, aq0[1]);
            aq1[0] = mfma16(F0[ks],   bq1, aq1[0]);  aq1[1] = mfma16(F1[ks],   bq1, aq1[1]);
            ak0[0] = mfma16(F0[ks+4], bk0, ak0[0]);  ak0[1] = mfma16(F1[ks+4], bk0, ak0[1]);
            ak1[0] = mfma16(F0[ks+4], bk1, ak1[0]);  ak1[1] = mfma16(F1[ks+4], bk1, ak1[1]);
        }
        float qb0 = q_b[c0], qb1 = q_b[c1], kb0 = k_b[c0], kb1 = k_b[c1];
        float p[2][4];
        #pragma unroll
        for (int r=0;r<2;r++){
            #pragma unroll
            for (int j=0;j<4;j++)
                p[r][j] = ((r?aq0[1]:aq0[0])[j]+qb0)*((r?ak0[1]:ak0[0])[j]+kb0)
                        + ((r?aq1[1]:aq1[0])[j]+qb1)*((r?ak1[1]:ak1[0])[j]+kb1);
        }
        #pragma unroll
        for (int m=1;m<16;m<<=1){
            #pragma unroll
            for (int r=0;r<2;r++){
                #pragma unroll
                for (int j=0;j<4;j++)
                    p[r][j] += __shfl_xor(p[r][j], m);
            }
        }
        if (l15 == 0){
            #pragma unroll
            for (int r=0;r<2;r++){
                #pragma unroll
                for (int j=0;j<4;j++)
                    part[r*16+lj+j][w] = p[r][j];
            }
        }
    }
    __syncthreads();                    // S2

    // ---- softmax (tid<32) ∥ V MFMAs (regs) ∥ ENT (regs -> ebuf) ----
    if (tid < ET){
        const float sc = 0.17677669529663688f;   // 1/sqrt(32)
        float s0 = part[tid][0]*sc, s1 = part[tid][1]*sc;
        float s2 = part[tid][2]*sc, s3 = part[tid][3]*sc;
        float mx = fmaxf(fmaxf(s0,s1),fmaxf(s2,s3));
        s0=expf(s0-mx); s1=expf(s1-mx); s2=expf(s2-mx); s3=expf(s3-mx);
        float inv = 1.0f/(s0+s1+s2+s3);
        swv[tid][0]=s0*inv; swv[tid][1]=s1*inv; swv[tid][2]=s2*inv; swv[tid][3]=s3*inv;
    }
    f32x4 av0[2], av1[2];
    {
        #pragma unroll
        for (int r=0;r<2;r++){ av0[r]=(f32x4){0,0,0,0}; av1[r]=(f32x4){0,0,0,0}; }
        #pragma unroll
        for (int ks=0; ks<4; ks++){
            short8 bv0 = bfrag(wV,128,ct0,ks,lane);
            short8 bv1 = bfrag(wV,128,ct1,ks,lane);
            av0[0] = mfma16(F0[ks+4], bv0, av0[0]);  av0[1] = mfma16(F1[ks+4], bv0, av0[1]);
            av1[0] = mfma16(F0[ks+4], bv1, av1[0]);  av1[1] = mfma16(F1[ks+4], bv1, av1[1]);
        }
    }
    // ---- ENT: 4 col-tiles per wave (ct = 4w+t), K=256 from regs -> ebuf ----
    #pragma unroll 1
    for (int t=0; t<4; t++){
        const int ct = 4*w + t;
        f32x4 ae0=(f32x4){0,0,0,0}, ae1=(f32x4){0,0,0,0};
        #pragma unroll
        for (int ks=0; ks<8; ks++){
            short8 b0 = bfrag(wE,256,ct,ks,lane);
            ae0 = mfma16(F0[ks], b0, ae0);
            ae1 = mfma16(F1[ks], b0, ae1);
        }
        float bb = ent_b[ct*16 + l15];
        const int cc = ct*16 + l15;
        #pragma unroll
        for (int j=0;j<4;j++){
            ebuf[(C32(lj+j,    cc>>3)<<3) + (cc&7)] = f2bf(ae0[j] + bb);
            ebuf[(C32(16+lj+j, cc>>3)<<3) + (cc&7)] = f2bf(ae1[j] + bb);
        }
    }
    __syncthreads();                    // S3 (swv ready AND ebuf ready)

    // ---- qm = swv*(v+b) ----
    f32x4 qm0[2], qm1[2];
    {
        float vb0 = v_b[c0], vb1 = v_b[c1];
        #pragma unroll
        for (int r=0;r<2;r++){
            #pragma unroll
            for (int j=0;j<4;j++){
                float sw = swv[r*16+lj+j][w];
                (r?qm0[1]:qm0[0])[j] = ((r?av0[1]:av0[0])[j] + vb0) * sw;
                (r?qm1[1]:qm1[0])[j] = ((r?av1[1]:av1[0])[j] + vb1) * sw;
            }
        }
    }

    // ---- load E-frags once (16 reads); MEAS fully from regs ----
    {
        const short8* ebv = (const short8*)ebuf;
        short8 E0[8], E1[8];
        #pragma unroll
        for (int ks=0; ks<8; ks++){
            E0[ks] = ebv[C32(l15,    (ks<<2)+lh)];
            E1[ks] = ebv[C32(16+l15, (ks<<2)+lh)];
        }
        #pragma unroll 1
        for (int kk=0; kk<4; kk++){
            const short* wMk = wM + (long)kk*16384;
            #pragma unroll
            for (int ci=0; ci<2; ci++){
                const int ct = 2*w + ci;
                short8 bm[4];
                #pragma unroll
                for (int ks=0;ks<4;ks++) bm[ks] = bfrag(wMk, 128, ct, ks, lane);
                float mb = meas_b[kk*128 + ct*16 + l15];
                #pragma unroll
                for (int r=0;r<2;r++){
                    f32x4 mi=(f32x4){0,0,0,0}, mj=(f32x4){0,0,0,0};
                    #pragma unroll
                    for (int ks=0;ks<4;ks++){
                        mi = mfma16(r ? E1[ks]   : E0[ks],   bm[ks], mi);
                        mj = mfma16(r ? E1[ks+4] : E0[ks+4], bm[ks], mj);
                    }
                    #pragma unroll
                    for (int j=0;j<4;j++){
                        float add = 0.25f*(mi[j]+mb)*(mj[j]+mb);
                        if (ci) (r?qm1[1]:qm1[0])[j] += add;
                        else    (r?qm0[1]:qm0[0])[j] += add;
                    }
                }
            }
        }
    }
    // ---- write msg-in bf16 to msgb (overlays xin; xin LDS dead since F-load) ----
    {
        #pragma unroll
        for (int r=0;r<2;r++){
            #pragma unroll
            for (int j=0;j<4;j++){
                int row = r*16 + lj + j;
                msgb[(C16(row, c0>>3)<<3) + (c0&7)] = f2bf((r?qm0[1]:qm0[0])[j]);
                msgb[(C16(row, c1>>3)<<3) + (c1&7)] = f2bf((r?qm1[1]:qm1[0])[j]);
            }
        }
    }
    __syncthreads();                    // S4 (ebuf dead after E-load; msgb ready)

    // ---- OUT: msg = msgb@Wo^T + b -> msgF (f32, stride 132, overlays ebuf) ----
    {
        const short8* mbv = (const short8*)msgb;
        f32x4 ao0[2], ao1[2];
        #pragma unroll
        for (int r=0;r<2;r++){ ao0[r]=(f32x4){0,0,0,0}; ao1[r]=(f32x4){0,0,0,0}; }
        #pragma unroll
        for (int ks=0; ks<4; ks++){
            short8 bo0 = bfrag(wO,128,ct0,ks,lane);
            short8 bo1 = bfrag(wO,128,ct1,ks,lane);
            short8 fa0 = mbv[C16(l15,    (ks<<2)+lh)];
            short8 fa1 = mbv[C16(16+l15, (ks<<2)+lh)];
            ao0[0] = mfma16(fa0, bo0, ao0[0]);  ao0[1] = mfma16(fa1, bo0, ao0[1]);
            ao1[0] = mfma16(fa0, bo1, ao1[0]);  ao1[1] = mfma16(fa1, bo1, ao1[1]);
        }
        float ob0 = out_b[c0], ob1 = out_b[c1];
        #pragma unroll
        for (int r=0;r<2;r++){
            #pragma unroll
            for (int j=0;j<4;j++){
                int row = r*16 + lj + j;
                msgF[row*132 + c0] = (r?ao0[1]:ao0[0])[j] + ob0;
                msgF[row*132 + c1] = (r?ao1[1]:ao1[0])[j] + ob1;
            }
        }
    }
    __syncthreads();                    // S5

    // ---- per-tile segmented reduction over sorted tgt runs ----
    if (tid < 128){
        const int c = tid;
        const int tgPrev = tgPrevS, tgNext = tgNextS;
        float acc = 0.f;
        int runStart = 0;
        #pragma unroll 4
        for (int r=0; r<ET; r++){
            acc += msgF[r*132 + c];
            bool last = (r==ET-1) || (tg[r+1] != tg[r]);
            if (last){
                int node = tg[r];
                bool openL = (runStart==0) && (tgPrev == node);
                bool openR = (r==ET-1)     && (tgNext == node);
                if (openL || openR) atomicAdd(&agg[(long)node*128 + c], acc);
                else                agg[(long)node*128 + c] = acc;
                acc = 0.f; runStart = r+1;
            }
        }
    }
}

// ---------------- Stage 3: LN + exact gelu, in place on d_out ----------------
__global__ __launch_bounds__(256) void final_kernel(
    const float* __restrict__ g2, const float* __restrict__ b2,
    float* __restrict__ io)
{
    const int lane = threadIdx.x & 63;
    const int n = blockIdx.x*4 + (threadIdx.x>>6);
    float v0 = io[(long)n*128 + lane];
    float v1 = io[(long)n*128 + 64 + lane];
    float s = v0+v1, sq = v0*v0 + v1*v1;
    #pragma unroll
    for (int m=1;m<64;m<<=1){ s += __shfl_xor(s,m); sq += __shfl_xor(sq,m); }
    float mean = s*(1.0f/128.0f);
    float rstd = rsqrtf(sq*(1.0f/128.0f)-mean*mean+1e-5f);
    float y0 = (v0-mean)*rstd*g2[lane]    + b2[lane];
    float y1 = (v1-mean)*rstd*g2[64+lane] + b2[64+lane];
    io[(long)n*128+lane]    = 0.5f*y0*(1.0f+erff(y0*0.70710678118f));
    io[(long)n*128+64+lane] = 0.5f*y1*(1.0f+erff(y1*0.70710678118f));
}

extern "C" void kernel_launch(void* const* d_in, const int* in_sizes, int n_in,
                              void* d_out, int out_size, void* d_ws, size_t ws_size,
                              hipStream_t stream)
{
    const float* x      = (const float*)d_in[0];
    const int*   eidx   = (const int*)  d_in[1];
    const float* sp_w   = (const float*)d_in[2];
    const float* sp_b   = (const float*)d_in[3];
    const float* ln1_g  = (const float*)d_in[4];
    const float* ln1_b  = (const float*)d_in[5];
    const float* pg     = (const float*)d_in[6];
    const float* amp_w  = (const float*)d_in[7];
    const float* amp_b  = (const float*)d_in[8];
    const float* ph_w   = (const float*)d_in[9];
    const float* ph_b   = (const float*)d_in[10];
    const float* ent_w  = (const float*)d_in[11];
    const float* ent_b  = (const float*)d_in[12];
    const float* q_w    = (const float*)d_in[13];
    const float* q_b    = (const float*)d_in[14];
    const float* k_w    = (const float*)d_in[15];
    const float* k_b    = (const float*)d_in[16];
    const float* v_w    = (const float*)d_in[17];
    const float* v_b    = (const float*)d_in[18];
    const float* meas_w = (const float*)d_in[19];
    const float* meas_b = (const float*)d_in[20];
    const float* out_w  = (const float*)d_in[21];
    const float* out_b  = (const float*)d_in[22];
    const float* ln2_g  = (const float*)d_in[23];
    const float* ln2_b  = (const float*)d_in[24];

    char* wsb = (char*)d_ws;
    short* qfb  = (short*)wsb;                      // 25,600,000 B
    short* wAll = (short*)(wsb + 25600000);         //    442,368 B (221184 bf16)
    int* hist   = (int*)(wsb + 26042368);           //    401,408 B
    int* cnt    = (int*)(wsb + 26443776);           //    401,408 B
    int* scanv  = (int*)(wsb + 26845184);           //    401,408 B
    int* bsum   = (int*)(wsb + 27246592);           //      1,024 B
    int* boff   = (int*)(wsb + 27247616);           //      1,024 B
    int* sTgt   = (int*)(wsb + 27248640);           //  2,000,000 B
    int* sSrc   = (int*)(wsb + 29248640);           //  2,000,000 B -> 31.25 MB

    short* wE  = wAll;                              // 256*256
    short* wQ  = wE + 65536;                        // 128*128
    short* wK  = wQ + 16384;
    short* wV  = wK + 16384;
    short* wM  = wV + 16384;                        // 4*128*128
    short* wO  = wM + 65536;                        // 128*128
    short* wSP = wO + 16384;                        // 128*128
    short* wA  = wSP + 16384;                       // 64*64
    short* wP  = wA + 4096;                         // 64*64

    float* agg = (float*)d_out;

    hipMemsetAsync(d_out, 0, (size_t)NN*128*sizeof(float), stream);
    hipMemsetAsync(hist, 0, 401408, stream);
    hipMemsetAsync(cnt,  0, 401408, stream);

    prep_kernel<<<864, 256, 0, stream>>>(ent_w, q_w, k_w, v_w, meas_w, out_w,
                                         sp_w, amp_w, ph_w, wAll);
    node_kernel<<<NNB, 512, 0, stream>>>(x, wSP, sp_b, ln1_g, ln1_b, pg,
                                         wA, amp_b, wP, ph_b, qfb);
    hist_kernel<<<(EE+255)/256, 256, 0, stream>>>(eidx, hist);
    scanA_kernel<<<196, 512, 0, stream>>>(hist, scanv, bsum);
    scanB_kernel<<<1, 256, 0, stream>>>(bsum, boff);
    scatter_kernel<<<(EE+255)/256, 256, 0, stream>>>(eidx, scanv, boff, cnt, sTgt, sSrc);
    edge_kernel<<<NEB, 256, 0, stream>>>(qfb, sTgt, sSrc,
                                         wE, ent_b, wQ, q_b, wK, k_b, wV, v_b,
                                         wM, meas_b, wO, out_b, agg);
    final_kernel<<<NN/4, 256, 0, stream>>>(ln2_g, ln2_b, agg);
}